// Round 11
// baseline (399.939 us; speedup 1.0000x reference)
//
#include <hip/hip_runtime.h>
#include <hip/hip_bf16.h>
#include <math.h>

typedef __hip_bfloat16 bf16;
typedef __attribute__((ext_vector_type(8))) short short8;
typedef __attribute__((ext_vector_type(4))) short short4v;
typedef __attribute__((ext_vector_type(4))) float floatx4;

#define D_MODEL 1024
#define SEQ     2048
#define BATCH   2
#define NHEAD   16
#define HDIM    64
#define FFDIM   4096
#define ROWS    (BATCH*SEQ)   // 4096 token rows

__device__ __forceinline__ void stv(bf16* p, float v)  { *p = __float2bfloat16(v); }
__device__ __forceinline__ void stv(float* p, float v) { *p = v; }

__device__ __forceinline__ void load_lds16(const bf16* g, bf16* l) {
  __builtin_amdgcn_global_load_lds((const __attribute__((address_space(1))) void*)g,
                                   (__attribute__((address_space(3))) void*)l, 16, 0, 0);
}

// fast GELU: x * sigmoid(x*(c0 + c1*x^2)) == tanh-form GELU; max |err| vs exact ~4e-4
// log2(e) folded into the polynomial so we can use raw v_exp_f32 (exp2).
__device__ __forceinline__ float gelu_fast(float x) {
  float z = x * (2.3022151f + 0.10294319f * x * x);
  return x * __builtin_amdgcn_rcpf(1.0f + __builtin_amdgcn_exp2f(-z));
}

// ---------------- LayerNorm: one 256-thread block per row of 1024 ----------------
__global__ void ln_kernel(const float* __restrict__ x, const float* __restrict__ g,
                          const float* __restrict__ beta, bf16* __restrict__ out) {
  const int row = blockIdx.x;
  const int tid = threadIdx.x;
  __shared__ float red[8];
  const float4 v = ((const float4*)(x + (size_t)row * D_MODEL))[tid];
  float s  = v.x + v.y + v.z + v.w;
  float ss = v.x * v.x + v.y * v.y + v.z * v.z + v.w * v.w;
#pragma unroll
  for (int off = 32; off > 0; off >>= 1) {
    s  += __shfl_down(s, off);
    ss += __shfl_down(ss, off);
  }
  if ((tid & 63) == 0) { red[tid >> 6] = s; red[4 + (tid >> 6)] = ss; }
  __syncthreads();
  s  = red[0] + red[1] + red[2] + red[3];
  ss = red[4] + red[5] + red[6] + red[7];
  const float mu  = s * (1.0f / D_MODEL);
  const float var = ss * (1.0f / D_MODEL) - mu * mu;
  const float rs  = rsqrtf(var + 1e-5f);
  const float4 g4 = ((const float4*)g)[tid];
  const float4 b4 = ((const float4*)beta)[tid];
  bf16 ov[4];
  ov[0] = __float2bfloat16((v.x - mu) * rs * g4.x + b4.x);
  ov[1] = __float2bfloat16((v.y - mu) * rs * g4.y + b4.y);
  ov[2] = __float2bfloat16((v.z - mu) * rs * g4.z + b4.z);
  ov[3] = __float2bfloat16((v.w - mu) * rs * g4.w + b4.w);
  ((short4v*)(out + (size_t)row * D_MODEL))[tid] = *(const short4v*)ov;
}

// -------- W[K][N] f32 -> Wt[N][K] bf16, two jobs batched in one dispatch --------
__device__ __forceinline__ void convert_tile(const float* W, bf16* Wt,
                                             int K, int N, int n0, int k0, int tid) {
  __shared__ float tile[64][65];
  const int r = tid >> 2, c0 = (tid & 3) * 16;
#pragma unroll
  for (int j = 0; j < 16; j += 4) {
    float4 v = *(const float4*)&W[(size_t)(k0 + r) * N + n0 + c0 + j];
    tile[r][c0 + j]     = v.x; tile[r][c0 + j + 1] = v.y;
    tile[r][c0 + j + 2] = v.z; tile[r][c0 + j + 3] = v.w;
  }
  __syncthreads();
  bf16 ov[16];
#pragma unroll
  for (int j = 0; j < 16; j++) ov[j] = __float2bfloat16(tile[c0 + j][r]);
  *(short8*)&Wt[(size_t)(n0 + r) * K + k0 + c0]     = *(const short8*)&ov[0];
  *(short8*)&Wt[(size_t)(n0 + r) * K + k0 + c0 + 8] = *(const short8*)&ov[8];
}

__global__ __launch_bounds__(256) void convert_w2(
    const float* __restrict__ W0, bf16* __restrict__ Wt0, int K0, int N0, int tiles0,
    const float* __restrict__ W1, bf16* __restrict__ Wt1, int K1, int N1) {
  int bid = blockIdx.x;
  const int tid = threadIdx.x;
  if (bid < tiles0) {
    const int nt = N0 >> 6;
    convert_tile(W0, Wt0, K0, N0, (bid % nt) * 64, (bid / nt) * 64, tid);
  } else {
    bid -= tiles0;
    const int nt = N1 >> 6;
    convert_tile(W1, Wt1, K1, N1, (bid % nt) * 64, (bid / nt) * 64, tid);
  }
}

// ------------- V-transpose: vT[h*64+d][b*2048+t] = qkv[b*2048+t][2048+h*64+d] ----
__global__ __launch_bounds__(256) void v_transpose(const bf16* __restrict__ qkv,
                                                   bf16* __restrict__ vT) {
  __shared__ bf16 tile[64][72];
  const int m0 = blockIdx.x * 64;
  const int d0 = blockIdx.y * 64;
  const int tid = threadIdx.x;
  const int r = tid >> 2, c0 = (tid & 3) * 16;
  *(short8*)&tile[r][c0]     = *(const short8*)&qkv[(size_t)(m0 + r) * 3072 + 2048 + d0 + c0];
  *(short8*)&tile[r][c0 + 8] = *(const short8*)&qkv[(size_t)(m0 + r) * 3072 + 2048 + d0 + c0 + 8];
  __syncthreads();
  bf16 ov[16];
#pragma unroll
  for (int j = 0; j < 16; j++) ov[j] = tile[c0 + j][r];
  *(short8*)&vT[(size_t)(d0 + r) * (size_t)ROWS + m0 + c0]     = *(const short8*)&ov[0];
  *(short8*)&vT[(size_t)(d0 + r) * (size_t)ROWS + m0 + c0 + 8] = *(const short8*)&ov[8];
}

// ------- Phase-split MFMA GEMM, square BMxBM tile (generalized gemm_256) -------
// BM=256/THREADS=512: 8 waves (2Mx4N), per-wave 128x64 = acc[8][4] (qkv, fc1).
// BM=128/THREADS=256: 4 waves (2Mx2N), per-wave  64x64 = acc[4][4] (proj, fc2)
//   -- per-wave LDS bytes/MFMA 0.375 KB vs 1.25 KB at the old 64x64 tile: the
//   fc2 fix (it was LDS-BW-bound: 2.6 GB of ds_reads ~= 53 us at the ceiling).
// K-tile loop (BK=64): 4 quadrant-phases, each {ds_read quadrant frags; stage 2
// gloads of next tile; barrier; setprio(1) MFMA setprio(0); barrier}; one
// vmcnt(0)+barrier per K-tile.  Sync-equivalent to the verified dbuf pattern.
template<int ACT, bool HAS_RES, int BM, int THREADS, typename OUT_T>
__global__ __launch_bounds__(THREADS, 2) void gemm_ps(
    const bf16* __restrict__ A, const bf16* __restrict__ Bt,
    const float* __restrict__ bias, const float* __restrict__ res,
    OUT_T* __restrict__ C, int M, int N, int K, int NTI) {
  constexpr int WAVES = THREADS / 64;
  constexpr int WN    = WAVES / 2;          // 4 (BM=256) or 2 (BM=128)
  constexpr int MFRAG = BM / (2 * 16);      // 8 or 4
  constexpr int NFRAG = BM / (WN * 16);     // 4 or 4
  constexpr int SROWS = THREADS / 8;        // 64 or 32 staging rows per call
  __shared__ __align__(16) bf16 As[2][BM][64];
  __shared__ __align__(16) bf16 Bs[2][BM][64];
  const int tid = threadIdx.x;
  const int w = tid >> 6, lane = tid & 63;
  const int quad = lane >> 4, l16 = lane & 15;
  const int wm = w / WN, wn = w % WN;
  // XCD-clustered decode: m-groups of 8 interleave across XCD slots
  const int bid = blockIdx.x;
  const int n_idx = (bid >> 3) % NTI;
  const int m_idx = ((bid >> 3) / NTI) * 8 + (bid & 7);
  const int m0 = m_idx * BM, n0 = n_idx * BM;
  const int srow = tid >> 3;                 // staging row in [0,SROWS)
  const int csw = (tid & 7) ^ (srow & 7);    // pre-swizzled global col slot

  const bf16* Ag = A  + (size_t)(m0 + srow) * K + csw * 8;
  const bf16* Bg = Bt + (size_t)(n0 + srow) * K + csw * 8;

  floatx4 acc[MFRAG][NFRAG];
#pragma unroll
  for (int i = 0; i < MFRAG; i++)
#pragma unroll
    for (int j = 0; j < NFRAG; j++) acc[i][j] = (floatx4){0.f, 0.f, 0.f, 0.f};

  const int sw = l16 & 7;
  const int KT = K >> 6;

  // prologue: stage tile 0 into buffer 0 (8 loads/thread)
#pragma unroll
  for (int j = 0; j < 4; j++)
    load_lds16(Ag + (size_t)j * SROWS * K, &As[0][j * SROWS + srow][0]);
#pragma unroll
  for (int j = 0; j < 4; j++)
    load_lds16(Bg + (size_t)j * SROWS * K, &Bs[0][j * SROWS + srow][0]);
  asm volatile("s_waitcnt vmcnt(0)" ::: "memory");
  __builtin_amdgcn_s_barrier();

  for (int kt = 0; kt < KT; kt++) {
    const int cur = kt & 1;
    const int kkn = (kt + 1) << 6;
    const bool hn = (kt + 1 < KT);
#pragma unroll
    for (int q = 0; q < 4; q++) {
      const int mf0 = (q >> 1) * (MFRAG / 2);
      const int nf0 = (q & 1) * (NFRAG / 2);
      short8 af[MFRAG / 2][2], bfr[NFRAG / 2][2];
#pragma unroll
      for (int i = 0; i < MFRAG / 2; i++)
#pragma unroll
        for (int hh = 0; hh < 2; hh++) {
          const int cc = ((quad + hh * 4) ^ sw) * 8;
          af[i][hh] = *(const short8*)&As[cur][wm * (MFRAG * 16) + (mf0 + i) * 16 + l16][cc];
        }
#pragma unroll
      for (int j = 0; j < NFRAG / 2; j++)
#pragma unroll
        for (int hh = 0; hh < 2; hh++) {
          const int cc = ((quad + hh * 4) ^ sw) * 8;
          bfr[j][hh] = *(const short8*)&Bs[cur][wn * (NFRAG * 16) + (nf0 + j) * 16 + l16][cc];
        }
      if (hn) {   // stage 2 loads of tile kt+1 into the freed buffer
        load_lds16(Ag + kkn + (size_t)q * SROWS * K, &As[cur ^ 1][q * SROWS + srow][0]);
        load_lds16(Bg + kkn + (size_t)q * SROWS * K, &Bs[cur ^ 1][q * SROWS + srow][0]);
      }
      __builtin_amdgcn_s_barrier();
      __builtin_amdgcn_s_setprio(1);
#pragma unroll
      for (int i = 0; i < MFRAG / 2; i++)
#pragma unroll
        for (int j = 0; j < NFRAG / 2; j++) {
          acc[mf0 + i][nf0 + j] = __builtin_amdgcn_mfma_f32_16x16x32_bf16(
              af[i][0], bfr[j][0], acc[mf0 + i][nf0 + j], 0, 0, 0);
          acc[mf0 + i][nf0 + j] = __builtin_amdgcn_mfma_f32_16x16x32_bf16(
              af[i][1], bfr[j][1], acc[mf0 + i][nf0 + j], 0, 0, 0);
        }
      __builtin_amdgcn_s_setprio(0);
      __builtin_amdgcn_s_barrier();
    }
    asm volatile("s_waitcnt vmcnt(0)" ::: "memory");   // tile kt+1 landed
    __builtin_amdgcn_s_barrier();                      // all waves done with cur
  }

  const int mb = m0 + wm * (MFRAG * 16) + quad * 4;
  const int nb = n0 + wn * (NFRAG * 16) + l16;
  float bv[NFRAG];
#pragma unroll
  for (int nf = 0; nf < NFRAG; nf++) bv[nf] = bias[nb + nf * 16];
#pragma unroll
  for (int mf = 0; mf < MFRAG; mf++) {
#pragma unroll
    for (int r = 0; r < 4; r++) {
      const int m = mb + mf * 16 + r;
#pragma unroll
      for (int nf = 0; nf < NFRAG; nf++) {
        const int n = nb + nf * 16;
        float val = acc[mf][nf][r] + bv[nf];
        if (ACT == 1) val = gelu_fast(val);
        if (HAS_RES) val += res[(size_t)m * N + n];
        stv(&C[(size_t)m * N + n], val);
      }
    }
  }
}

// ---------------- Flash attention, transposed form (S^T / O^T) ----------------
__global__ __launch_bounds__(256) void attn_mfma(const bf16* __restrict__ qkv,
                                                 const bf16* __restrict__ vT,
                                                 bf16* __restrict__ y) {
  const int bid  = blockIdx.x;
  const int slot = bid >> 3;
  const int hb   = (bid & 7) + 8 * (slot >> 4);   // [0,32): head-batch pair
  const int qt   = slot & 15;                     // [0,16): q-tile
  const int h = hb & 15, b = hb >> 4;
  const int tid  = threadIdx.x;
  const int wave = tid >> 6, lane = tid & 63;
  const int quad = lane >> 4, l16 = lane & 15;
  const int sw8  = l16 & 7;

  __shared__ __align__(16) bf16 Ks[2][2][64 * 64];   // [buf][half][k-row][d]
  __shared__ __align__(16) bf16 Vs[2][2][64 * 64];   // [buf][half][d][t]
  __shared__ __align__(16) bf16 Ps[4][32 * 64];

  const size_t base = (size_t)b * SEQ * 3072;
  const int q0 = qt * 128 + wave * 32;

  short8 qb[2][2];
#pragma unroll
  for (int qf = 0; qf < 2; qf++) {
    const bf16* qrow = qkv + base + (size_t)(q0 + qf * 16 + l16) * 3072 + h * HDIM;
    qb[qf][0] = *(const short8*)(qrow + quad * 8);
    qb[qf][1] = *(const short8*)(qrow + 32 + quad * 8);
    bf16* p0 = (bf16*)&qb[qf][0]; bf16* p1 = (bf16*)&qb[qf][1];
#pragma unroll
    for (int j = 0; j < 8; j++) {
      p0[j] = __float2bfloat16(__bfloat162float(p0[j]) * 0.18033688f);
      p1[j] = __float2bfloat16(__bfloat162float(p1[j]) * 0.18033688f);
    }
  }

  floatx4 O[2][4];
#pragma unroll
  for (int qf = 0; qf < 2; qf++)
#pragma unroll
    for (int c = 0; c < 4; c++) O[qf][c] = (floatx4){0.f, 0.f, 0.f, 0.f};
  floatx4 L[2];
  L[0] = (floatx4){0.f, 0.f, 0.f, 0.f};
  L[1] = (floatx4){0.f, 0.f, 0.f, 0.f};

  const int skey = tid >> 3, sc = tid & 7;
  const int gcol = (sc ^ (skey & 7)) * 8;
  const bf16* kg = qkv + base + D_MODEL + h * HDIM;
  const bf16* vg = vT + (size_t)(h * HDIM) * (size_t)ROWS + b * SEQ;

  auto stage = [&](int nb, int kt) {
#pragma unroll
    for (int kh = 0; kh < 2; kh++) {
      const int kb = kt + kh * 64;
      load_lds16(kg + (size_t)(kb + skey) * 3072 + gcol,      &Ks[nb][kh][tid * 8]);
      load_lds16(kg + (size_t)(kb + skey + 32) * 3072 + gcol, &Ks[nb][kh][(tid + 256) * 8]);
      load_lds16(vg + (size_t)skey * ROWS + kb + gcol,        &Vs[nb][kh][tid * 8]);
      load_lds16(vg + (size_t)(skey + 32) * ROWS + kb + gcol, &Vs[nb][kh][(tid + 256) * 8]);
    }
  };

  stage(0, 0);
  asm volatile("s_waitcnt vmcnt(0)" ::: "memory");
  __builtin_amdgcn_s_barrier();

  short8 onesv;
#pragma unroll
  for (int j = 0; j < 8; j++) ((short*)&onesv)[j] = (short)0x3f80;  // bf16 1.0

  int cur = 0;
  for (int kt = 0; kt < SEQ; kt += 128) {
    if (kt + 128 < SEQ) stage(cur ^ 1, kt + 128);

#pragma unroll
    for (int kh = 0; kh < 2; kh++) {
      const bf16* Kc = Ks[cur][kh];
      const bf16* Vc = Vs[cur][kh];

      floatx4 S[2][4];
#pragma unroll
      for (int g = 0; g < 4; g++) {
        const short8 ka0 = *(const short8*)&Kc[(g * 16 + l16) * 64 + ((quad    ) ^ sw8) * 8];
        const short8 ka1 = *(const short8*)&Kc[(g * 16 + l16) * 64 + ((quad + 4) ^ sw8) * 8];
#pragma unroll
        for (int qf = 0; qf < 2; qf++) {
          S[qf][g] = (floatx4){0.f, 0.f, 0.f, 0.f};
          S[qf][g] = __builtin_amdgcn_mfma_f32_16x16x32_bf16(ka0, qb[qf][0], S[qf][g], 0, 0, 0);
          S[qf][g] = __builtin_amdgcn_mfma_f32_16x16x32_bf16(ka1, qb[qf][1], S[qf][g], 0, 0, 0);
        }
      }

#pragma unroll
      for (int qf = 0; qf < 2; qf++)
#pragma unroll
        for (int g = 0; g < 4; g++) {
          bf16 pb4[4];
#pragma unroll
          for (int r = 0; r < 4; r++)
            pb4[r] = __float2bfloat16(__builtin_amdgcn_exp2f(S[qf][g][r]));
          const int chunk = 2 * g + (quad >> 1);
          *(short4v*)&Ps[wave][(qf * 16 + l16) * 64 + (chunk ^ sw8) * 8 + (quad & 1) * 4] =
              *(const short4v*)pb4;
        }

      short8 pb[2][2];
#pragma unroll
      for (int qf = 0; qf < 2; qf++) {
        pb[qf][0] = *(const short8*)&Ps[wave][(qf * 16 + l16) * 64 + ((quad    ) ^ sw8) * 8];
        pb[qf][1] = *(const short8*)&Ps[wave][(qf * 16 + l16) * 64 + ((quad + 4) ^ sw8) * 8];
        L[qf] = __builtin_amdgcn_mfma_f32_16x16x32_bf16(onesv, pb[qf][0], L[qf], 0, 0, 0);
        L[qf] = __builtin_amdgcn_mfma_f32_16x16x32_bf16(onesv, pb[qf][1], L[qf], 0, 0, 0);
      }

#pragma unroll
      for (int c = 0; c < 4; c++) {
        const short8 va0 = *(const short8*)&Vc[(c * 16 + l16) * 64 + ((quad    ) ^ sw8) * 8];
        const short8 va1 = *(const short8*)&Vc[(c * 16 + l16) * 64 + ((quad + 4) ^ sw8) * 8];
#pragma unroll
        for (int qf = 0; qf < 2; qf++) {
          O[qf][c] = __builtin_amdgcn_mfma_f32_16x16x32_bf16(va0, pb[qf][0], O[qf][c], 0, 0, 0);
          O[qf][c] = __builtin_amdgcn_mfma_f32_16x16x32_bf16(va1, pb[qf][1], O[qf][c], 0, 0, 0);
        }
      }
    }

    asm volatile("s_waitcnt vmcnt(0)" ::: "memory");
    __builtin_amdgcn_s_barrier();
    cur ^= 1;
  }

#pragma unroll
  for (int qf = 0; qf < 2; qf++) {
    const float inv = __builtin_amdgcn_rcpf(L[qf][0]);
    bf16* yrow = y + (size_t)(b * SEQ + q0 + qf * 16 + l16) * D_MODEL + h * HDIM + quad * 4;
#pragma unroll
    for (int c = 0; c < 4; c++) {
      bf16 ov[4];
#pragma unroll
      for (int r = 0; r < 4; r++) ov[r] = __float2bfloat16(O[qf][c][r] * inv);
      *(short4v*)(yrow + c * 16) = *(const short4v*)ov;
    }
  }
}

extern "C" void kernel_launch(void* const* d_in, const int* in_sizes, int n_in,
                              void* d_out, int out_size, void* d_ws, size_t ws_size,
                              hipStream_t stream) {
  const float* x      = (const float*)d_in[0];
  const float* ln1_g  = (const float*)d_in[1];
  const float* ln1_b  = (const float*)d_in[2];
  const float* ln2_g  = (const float*)d_in[3];
  const float* ln2_b  = (const float*)d_in[4];
  const float* w_qkv  = (const float*)d_in[5];
  const float* b_qkv  = (const float*)d_in[6];
  const float* w_proj = (const float*)d_in[7];
  const float* b_proj = (const float*)d_in[8];
  const float* w_fc1  = (const float*)d_in[9];
  const float* b_fc1  = (const float*)d_in[10];
  const float* w_fc2  = (const float*)d_in[11];
  const float* b_fc2  = (const float*)d_in[12];
  float* out = (float*)d_out;

  char* ws = (char*)d_ws;
  bf16*  h       = (bf16*)(ws);
  bf16*  qkv     = (bf16*)(ws + (8u  << 20));
  bf16*  wt_fc1  = (bf16*)(ws + (8u  << 20));
  bf16*  wt_fc2  = (bf16*)(ws + (16u << 20));
  bf16*  y       = (bf16*)(ws + (32u << 20));
  float* x1      = (float*)(ws + (40u << 20));
  bf16*  ffh     = (bf16*)(ws + (56u << 20));
  bf16*  wt_qkv  = (bf16*)(ws + (56u << 20));
  bf16*  wt_proj = (bf16*)(ws + (62u << 20));
  bf16*  vT      = (bf16*)(ws + (64u << 20));

  // qkv + proj weight converts (one dispatch)
  convert_w2<<<768 + 256, 256, 0, stream>>>(w_qkv, wt_qkv, 1024, 3072, 768,
                                            w_proj, wt_proj, 1024, 1024);
  // 1. h = LN1(x)
  ln_kernel<<<ROWS, 256, 0, stream>>>(x, ln1_g, ln1_b, h);
  // 2. qkv = h @ w_qkv + b_qkv   (256x256 phase-split, 16x12=192 blocks)
  gemm_ps<0, false, 256, 512, bf16><<<192, 512, 0, stream>>>(
      h, wt_qkv, b_qkv, nullptr, qkv, ROWS, 3072, D_MODEL, 12);
  // 2b. vT = V^T
  v_transpose<<<dim3(ROWS / 64, 1024 / 64), 256, 0, stream>>>(qkv, vT);
  // 3. y = softmax(q k^T / 8) v   (512 blocks, XCD co-located per (b,h))
  attn_mfma<<<512, 256, 0, stream>>>(qkv, vT, y);
  // fc1 + fc2 weight converts (one dispatch; must follow attn: overlays qkv)
  convert_w2<<<1024 + 1024, 256, 0, stream>>>(w_fc1, wt_fc1, 1024, 4096, 1024,
                                              w_fc2, wt_fc2, 4096, 1024);
  // 4. x1 = x + y @ w_proj + b_proj   (128x128 phase-split, 32x8=256 blocks)
  gemm_ps<0, true, 128, 256, float><<<256, 256, 0, stream>>>(
      y, wt_proj, b_proj, x, x1, ROWS, D_MODEL, D_MODEL, 8);
  // 5. h = LN2(x1)
  ln_kernel<<<ROWS, 256, 0, stream>>>(x1, ln2_g, ln2_b, h);
  // 6. ffh = gelu(h @ w_fc1 + b_fc1)   (256x256 phase-split, 16x16=256 blocks)
  gemm_ps<1, false, 256, 512, bf16><<<256, 512, 0, stream>>>(
      h, wt_fc1, b_fc1, nullptr, ffh, ROWS, FFDIM, D_MODEL, 16);
  // 7. out = x1 + ffh @ w_fc2 + b_fc2   (128x128 phase-split, 32x8=256 blocks)
  gemm_ps<0, true, 128, 256, float><<<256, 256, 0, stream>>>(
      ffh, wt_fc2, b_fc2, x1, out, ROWS, D_MODEL, FFDIM, 8);
}

// Round 12
// 330.114 us; speedup vs baseline: 1.2115x; 1.2115x over previous
//
#include <hip/hip_runtime.h>
#include <hip/hip_bf16.h>
#include <math.h>

typedef __hip_bfloat16 bf16;
typedef __attribute__((ext_vector_type(8))) short short8;
typedef __attribute__((ext_vector_type(4))) short short4v;
typedef __attribute__((ext_vector_type(4))) float floatx4;

#define D_MODEL 1024
#define SEQ     2048
#define BATCH   2
#define NHEAD   16
#define HDIM    64
#define FFDIM   4096
#define ROWS    (BATCH*SEQ)   // 4096 token rows

__device__ __forceinline__ void stv(bf16* p, float v)  { *p = __float2bfloat16(v); }
__device__ __forceinline__ void stv(float* p, float v) { *p = v; }

__device__ __forceinline__ void load_lds16(const bf16* g, bf16* l) {
  __builtin_amdgcn_global_load_lds((const __attribute__((address_space(1))) void*)g,
                                   (__attribute__((address_space(3))) void*)l, 16, 0, 0);
}

// fast GELU: x * sigmoid(x*(c0 + c1*x^2)) == tanh-form GELU; max |err| vs exact ~4e-4
// log2(e) folded into the polynomial so we can use raw v_exp_f32 (exp2).
__device__ __forceinline__ float gelu_fast(float x) {
  float z = x * (2.3022151f + 0.10294319f * x * x);
  return x * __builtin_amdgcn_rcpf(1.0f + __builtin_amdgcn_exp2f(-z));
}

// ---------------- LayerNorm: one 256-thread block per row of 1024 ----------------
__global__ void ln_kernel(const float* __restrict__ x, const float* __restrict__ g,
                          const float* __restrict__ beta, bf16* __restrict__ out) {
  const int row = blockIdx.x;
  const int tid = threadIdx.x;
  __shared__ float red[8];
  const float4 v = ((const float4*)(x + (size_t)row * D_MODEL))[tid];
  float s  = v.x + v.y + v.z + v.w;
  float ss = v.x * v.x + v.y * v.y + v.z * v.z + v.w * v.w;
#pragma unroll
  for (int off = 32; off > 0; off >>= 1) {
    s  += __shfl_down(s, off);
    ss += __shfl_down(ss, off);
  }
  if ((tid & 63) == 0) { red[tid >> 6] = s; red[4 + (tid >> 6)] = ss; }
  __syncthreads();
  s  = red[0] + red[1] + red[2] + red[3];
  ss = red[4] + red[5] + red[6] + red[7];
  const float mu  = s * (1.0f / D_MODEL);
  const float var = ss * (1.0f / D_MODEL) - mu * mu;
  const float rs  = rsqrtf(var + 1e-5f);
  const float4 g4 = ((const float4*)g)[tid];
  const float4 b4 = ((const float4*)beta)[tid];
  bf16 ov[4];
  ov[0] = __float2bfloat16((v.x - mu) * rs * g4.x + b4.x);
  ov[1] = __float2bfloat16((v.y - mu) * rs * g4.y + b4.y);
  ov[2] = __float2bfloat16((v.z - mu) * rs * g4.z + b4.z);
  ov[3] = __float2bfloat16((v.w - mu) * rs * g4.w + b4.w);
  ((short4v*)(out + (size_t)row * D_MODEL))[tid] = *(const short4v*)ov;
}

// -------- W[K][N] f32 -> Wt[N][K] bf16, two jobs batched in one dispatch --------
__device__ __forceinline__ void convert_tile(const float* W, bf16* Wt,
                                             int K, int N, int n0, int k0, int tid) {
  __shared__ float tile[64][65];
  const int r = tid >> 2, c0 = (tid & 3) * 16;
#pragma unroll
  for (int j = 0; j < 16; j += 4) {
    float4 v = *(const float4*)&W[(size_t)(k0 + r) * N + n0 + c0 + j];
    tile[r][c0 + j]     = v.x; tile[r][c0 + j + 1] = v.y;
    tile[r][c0 + j + 2] = v.z; tile[r][c0 + j + 3] = v.w;
  }
  __syncthreads();
  bf16 ov[16];
#pragma unroll
  for (int j = 0; j < 16; j++) ov[j] = __float2bfloat16(tile[c0 + j][r]);
  *(short8*)&Wt[(size_t)(n0 + r) * K + k0 + c0]     = *(const short8*)&ov[0];
  *(short8*)&Wt[(size_t)(n0 + r) * K + k0 + c0 + 8] = *(const short8*)&ov[8];
}

__global__ __launch_bounds__(256) void convert_w2(
    const float* __restrict__ W0, bf16* __restrict__ Wt0, int K0, int N0, int tiles0,
    const float* __restrict__ W1, bf16* __restrict__ Wt1, int K1, int N1) {
  int bid = blockIdx.x;
  const int tid = threadIdx.x;
  if (bid < tiles0) {
    const int nt = N0 >> 6;
    convert_tile(W0, Wt0, K0, N0, (bid % nt) * 64, (bid / nt) * 64, tid);
  } else {
    bid -= tiles0;
    const int nt = N1 >> 6;
    convert_tile(W1, Wt1, K1, N1, (bid % nt) * 64, (bid / nt) * 64, tid);
  }
}

// ------------- V-transpose: vT[h*64+d][b*2048+t] = qkv[b*2048+t][2048+h*64+d] ----
__global__ __launch_bounds__(256) void v_transpose(const bf16* __restrict__ qkv,
                                                   bf16* __restrict__ vT) {
  __shared__ bf16 tile[64][72];
  const int m0 = blockIdx.x * 64;
  const int d0 = blockIdx.y * 64;
  const int tid = threadIdx.x;
  const int r = tid >> 2, c0 = (tid & 3) * 16;
  *(short8*)&tile[r][c0]     = *(const short8*)&qkv[(size_t)(m0 + r) * 3072 + 2048 + d0 + c0];
  *(short8*)&tile[r][c0 + 8] = *(const short8*)&qkv[(size_t)(m0 + r) * 3072 + 2048 + d0 + c0 + 8];
  __syncthreads();
  bf16 ov[16];
#pragma unroll
  for (int j = 0; j < 16; j++) ov[j] = tile[c0 + j][r];
  *(short8*)&vT[(size_t)(d0 + r) * (size_t)ROWS + m0 + c0]     = *(const short8*)&ov[0];
  *(short8*)&vT[(size_t)(d0 + r) * (size_t)ROWS + m0 + c0 + 8] = *(const short8*)&ov[8];
}

// ------- 256x256 phase-split MFMA GEMM (wide GEMMs: qkv, fc1) -----------------
// 512 threads = 8 waves (2Mx4N); per-wave C = 128x64 = acc[8][4].  Verified in
// rounds 10/11.  ONLY instantiated at BM=256/THREADS=512: the BM=128/4-wave
// variant measured 105us (1 wave/SIMD -> every phase barrier fully exposed).
template<int ACT, typename OUT_T>
__global__ __launch_bounds__(512, 2) void gemm_256(
    const bf16* __restrict__ A, const bf16* __restrict__ Bt,
    const float* __restrict__ bias, OUT_T* __restrict__ C,
    int M, int N, int K, int NTI) {
  __shared__ __align__(16) bf16 As[2][256][64];
  __shared__ __align__(16) bf16 Bs[2][256][64];
  const int tid = threadIdx.x;
  const int w = tid >> 6, lane = tid & 63;
  const int quad = lane >> 4, l16 = lane & 15;
  const int wm = w >> 2, wn = w & 3;
  const int bid = blockIdx.x;
  const int n_idx = (bid >> 3) % NTI;
  const int m_idx = ((bid >> 3) / NTI) * 8 + (bid & 7);
  const int m0 = m_idx * 256, n0 = n_idx * 256;
  const int srow = tid >> 3;
  const int csw = (tid & 7) ^ (srow & 7);

  const bf16* Ag = A  + (size_t)(m0 + srow) * K + csw * 8;
  const bf16* Bg = Bt + (size_t)(n0 + srow) * K + csw * 8;

  floatx4 acc[8][4];
#pragma unroll
  for (int i = 0; i < 8; i++)
#pragma unroll
    for (int j = 0; j < 4; j++) acc[i][j] = (floatx4){0.f, 0.f, 0.f, 0.f};

  const int sw = l16 & 7;
  const int KT = K >> 6;

#pragma unroll
  for (int j = 0; j < 4; j++)
    load_lds16(Ag + (size_t)j * 64 * K, &As[0][j * 64 + srow][0]);
#pragma unroll
  for (int j = 0; j < 4; j++)
    load_lds16(Bg + (size_t)j * 64 * K, &Bs[0][j * 64 + srow][0]);
  asm volatile("s_waitcnt vmcnt(0)" ::: "memory");
  __builtin_amdgcn_s_barrier();

  for (int kt = 0; kt < KT; kt++) {
    const int cur = kt & 1;
    const int kkn = (kt + 1) << 6;
    const bool hn = (kt + 1 < KT);
#pragma unroll
    for (int q = 0; q < 4; q++) {
      const int mf0 = (q >> 1) * 4;
      const int nf0 = (q & 1) * 2;
      short8 af[4][2], bfr[2][2];
#pragma unroll
      for (int i = 0; i < 4; i++)
#pragma unroll
        for (int hh = 0; hh < 2; hh++) {
          const int cc = ((quad + hh * 4) ^ sw) * 8;
          af[i][hh] = *(const short8*)&As[cur][wm * 128 + (mf0 + i) * 16 + l16][cc];
        }
#pragma unroll
      for (int j = 0; j < 2; j++)
#pragma unroll
        for (int hh = 0; hh < 2; hh++) {
          const int cc = ((quad + hh * 4) ^ sw) * 8;
          bfr[j][hh] = *(const short8*)&Bs[cur][wn * 64 + (nf0 + j) * 16 + l16][cc];
        }
      if (hn) {
        load_lds16(Ag + kkn + (size_t)q * 64 * K, &As[cur ^ 1][q * 64 + srow][0]);
        load_lds16(Bg + kkn + (size_t)q * 64 * K, &Bs[cur ^ 1][q * 64 + srow][0]);
      }
      __builtin_amdgcn_s_barrier();
      __builtin_amdgcn_s_setprio(1);
#pragma unroll
      for (int i = 0; i < 4; i++)
#pragma unroll
        for (int j = 0; j < 2; j++) {
          acc[mf0 + i][nf0 + j] = __builtin_amdgcn_mfma_f32_16x16x32_bf16(
              af[i][0], bfr[j][0], acc[mf0 + i][nf0 + j], 0, 0, 0);
          acc[mf0 + i][nf0 + j] = __builtin_amdgcn_mfma_f32_16x16x32_bf16(
              af[i][1], bfr[j][1], acc[mf0 + i][nf0 + j], 0, 0, 0);
        }
      __builtin_amdgcn_s_setprio(0);
      __builtin_amdgcn_s_barrier();
    }
    asm volatile("s_waitcnt vmcnt(0)" ::: "memory");
    __builtin_amdgcn_s_barrier();
  }

  const int mb = m0 + wm * 128 + quad * 4;
  const int nb = n0 + wn * 64 + l16;
  float bv[4];
#pragma unroll
  for (int nf = 0; nf < 4; nf++) bv[nf] = bias[nb + nf * 16];
#pragma unroll
  for (int mf = 0; mf < 8; mf++) {
#pragma unroll
    for (int r = 0; r < 4; r++) {
      const int m = mb + mf * 16 + r;
#pragma unroll
      for (int nf = 0; nf < 4; nf++) {
        const int n = nb + nf * 16;
        float val = acc[mf][nf][r] + bv[nf];
        if (ACT == 1) val = gelu_fast(val);
        stv(&C[(size_t)m * N + n], val);
      }
    }
  }
}

// ------- 64x64 dbuf GEMM, 2x2 wave split (narrow-N GEMMs: proj, fc2) ----------
// 1-deep double-buffered LDS (best-measured structure: grid 1024 = 4 blocks/CU,
// 16 waves/CU), with waves as 2x2 of 32x32 instead of 4x1 of 16x64: per-wave
// 8 ds_read_b128 per 8 MFMA (was 10) -- cuts the binding LDS-read traffic
// 2.6 -> 2.1 GB (fc2 was LDS-BW-bound at 3.7 GB total ~= 53us).  Fragment
// mapping ported from the verified r6 gemm_ksplit.
template<bool HAS_RES, typename OUT_T>
__global__ __launch_bounds__(256) void gemm64(
    const bf16* __restrict__ A, const bf16* __restrict__ Bt,
    const float* __restrict__ bias, const float* __restrict__ res,
    OUT_T* __restrict__ C, int M, int N, int K, int NTI) {
  __shared__ __align__(16) bf16 As[2][64][64];
  __shared__ __align__(16) bf16 Bs[2][64][64];
  const int tid = threadIdx.x;
  const int w = tid >> 6, lane = tid & 63;
  const int quad = lane >> 4, l16 = lane & 15;
  const int wm = w >> 1, wn = w & 1;
  const int bid = blockIdx.x;
  const int n_idx = (bid >> 3) % NTI;
  const int m_idx = ((bid >> 3) / NTI) * 8 + (bid & 7);
  const int m0 = m_idx * 64, n0 = n_idx * 64;
  const int rb = lane >> 3, cb = lane & 7;
  const int csw = cb ^ rb;

  const bf16* Ag = A  + (size_t)(m0 + (tid >> 3)) * K + csw * 8;
  const bf16* Bg = Bt + (size_t)(n0 + (tid >> 3)) * K + csw * 8;

  floatx4 acc[2][2];
#pragma unroll
  for (int i = 0; i < 2; i++)
#pragma unroll
    for (int j = 0; j < 2; j++) acc[i][j] = (floatx4){0.f, 0.f, 0.f, 0.f};

  const int sw = l16 & 7;

  auto stage = [&](int buf, int kk) {
#pragma unroll
    for (int j = 0; j < 2; j++)
      load_lds16(Ag + kk + (size_t)j * 32 * K, &As[buf][j * 32 + (tid >> 3)][0]);
#pragma unroll
    for (int j = 0; j < 2; j++)
      load_lds16(Bg + kk + (size_t)j * 32 * K, &Bs[buf][j * 32 + (tid >> 3)][0]);
  };

  auto compute = [&](int buf) {
    short8 af[2][2], bfr[2][2];
#pragma unroll
    for (int t = 0; t < 2; t++)
#pragma unroll
      for (int hh = 0; hh < 2; hh++) {
        const int cc = ((quad + hh * 4) ^ sw) * 8;
        af[t][hh]  = *(const short8*)&As[buf][wm * 32 + t * 16 + l16][cc];
        bfr[t][hh] = *(const short8*)&Bs[buf][wn * 32 + t * 16 + l16][cc];
      }
#pragma unroll
    for (int mt = 0; mt < 2; mt++)
#pragma unroll
      for (int nt = 0; nt < 2; nt++) {
        acc[mt][nt] = __builtin_amdgcn_mfma_f32_16x16x32_bf16(af[mt][0], bfr[nt][0], acc[mt][nt], 0, 0, 0);
        acc[mt][nt] = __builtin_amdgcn_mfma_f32_16x16x32_bf16(af[mt][1], bfr[nt][1], acc[mt][nt], 0, 0, 0);
      }
  };

  stage(0, 0);
  asm volatile("s_waitcnt vmcnt(0)" ::: "memory");
  __builtin_amdgcn_s_barrier();
  int cur = 0;
  for (int k0 = 0; k0 < K; k0 += 64) {
    if (k0 + 64 < K) stage(cur ^ 1, k0 + 64);
    compute(cur);
    asm volatile("s_waitcnt vmcnt(0)" ::: "memory");
    __builtin_amdgcn_s_barrier();
    cur ^= 1;
  }

  const int mbase = m0 + wm * 32 + quad * 4;
  const int nbase = n0 + wn * 32 + l16;
  float bv[2];
#pragma unroll
  for (int nt = 0; nt < 2; nt++) bv[nt] = bias[nbase + nt * 16];
#pragma unroll
  for (int mt = 0; mt < 2; mt++) {
#pragma unroll
    for (int r = 0; r < 4; r++) {
      const int m = mbase + mt * 16 + r;
#pragma unroll
      for (int nt = 0; nt < 2; nt++) {
        const int n = nbase + nt * 16;
        float val = acc[mt][nt][r] + bv[nt];
        if (HAS_RES) val += res[(size_t)m * N + n];
        stv(&C[(size_t)m * N + n], val);
      }
    }
  }
}

// ---------------- Flash attention, transposed form (S^T / O^T) ----------------
__global__ __launch_bounds__(256) void attn_mfma(const bf16* __restrict__ qkv,
                                                 const bf16* __restrict__ vT,
                                                 bf16* __restrict__ y) {
  const int bid  = blockIdx.x;
  const int slot = bid >> 3;
  const int hb   = (bid & 7) + 8 * (slot >> 4);   // [0,32): head-batch pair
  const int qt   = slot & 15;                     // [0,16): q-tile
  const int h = hb & 15, b = hb >> 4;
  const int tid  = threadIdx.x;
  const int wave = tid >> 6, lane = tid & 63;
  const int quad = lane >> 4, l16 = lane & 15;
  const int sw8  = l16 & 7;

  __shared__ __align__(16) bf16 Ks[2][2][64 * 64];   // [buf][half][k-row][d]
  __shared__ __align__(16) bf16 Vs[2][2][64 * 64];   // [buf][half][d][t]
  __shared__ __align__(16) bf16 Ps[4][32 * 64];

  const size_t base = (size_t)b * SEQ * 3072;
  const int q0 = qt * 128 + wave * 32;

  short8 qb[2][2];
#pragma unroll
  for (int qf = 0; qf < 2; qf++) {
    const bf16* qrow = qkv + base + (size_t)(q0 + qf * 16 + l16) * 3072 + h * HDIM;
    qb[qf][0] = *(const short8*)(qrow + quad * 8);
    qb[qf][1] = *(const short8*)(qrow + 32 + quad * 8);
    bf16* p0 = (bf16*)&qb[qf][0]; bf16* p1 = (bf16*)&qb[qf][1];
#pragma unroll
    for (int j = 0; j < 8; j++) {
      p0[j] = __float2bfloat16(__bfloat162float(p0[j]) * 0.18033688f);
      p1[j] = __float2bfloat16(__bfloat162float(p1[j]) * 0.18033688f);
    }
  }

  floatx4 O[2][4];
#pragma unroll
  for (int qf = 0; qf < 2; qf++)
#pragma unroll
    for (int c = 0; c < 4; c++) O[qf][c] = (floatx4){0.f, 0.f, 0.f, 0.f};
  floatx4 L[2];
  L[0] = (floatx4){0.f, 0.f, 0.f, 0.f};
  L[1] = (floatx4){0.f, 0.f, 0.f, 0.f};

  const int skey = tid >> 3, sc = tid & 7;
  const int gcol = (sc ^ (skey & 7)) * 8;
  const bf16* kg = qkv + base + D_MODEL + h * HDIM;
  const bf16* vg = vT + (size_t)(h * HDIM) * (size_t)ROWS + b * SEQ;

  auto stage = [&](int nb, int kt) {
#pragma unroll
    for (int kh = 0; kh < 2; kh++) {
      const int kb = kt + kh * 64;
      load_lds16(kg + (size_t)(kb + skey) * 3072 + gcol,      &Ks[nb][kh][tid * 8]);
      load_lds16(kg + (size_t)(kb + skey + 32) * 3072 + gcol, &Ks[nb][kh][(tid + 256) * 8]);
      load_lds16(vg + (size_t)skey * ROWS + kb + gcol,        &Vs[nb][kh][tid * 8]);
      load_lds16(vg + (size_t)(skey + 32) * ROWS + kb + gcol, &Vs[nb][kh][(tid + 256) * 8]);
    }
  };

  stage(0, 0);
  asm volatile("s_waitcnt vmcnt(0)" ::: "memory");
  __builtin_amdgcn_s_barrier();

  short8 onesv;
#pragma unroll
  for (int j = 0; j < 8; j++) ((short*)&onesv)[j] = (short)0x3f80;  // bf16 1.0

  int cur = 0;
  for (int kt = 0; kt < SEQ; kt += 128) {
    if (kt + 128 < SEQ) stage(cur ^ 1, kt + 128);

#pragma unroll
    for (int kh = 0; kh < 2; kh++) {
      const bf16* Kc = Ks[cur][kh];
      const bf16* Vc = Vs[cur][kh];

      floatx4 S[2][4];
#pragma unroll
      for (int g = 0; g < 4; g++) {
        const short8 ka0 = *(const short8*)&Kc[(g * 16 + l16) * 64 + ((quad    ) ^ sw8) * 8];
        const short8 ka1 = *(const short8*)&Kc[(g * 16 + l16) * 64 + ((quad + 4) ^ sw8) * 8];
#pragma unroll
        for (int qf = 0; qf < 2; qf++) {
          S[qf][g] = (floatx4){0.f, 0.f, 0.f, 0.f};
          S[qf][g] = __builtin_amdgcn_mfma_f32_16x16x32_bf16(ka0, qb[qf][0], S[qf][g], 0, 0, 0);
          S[qf][g] = __builtin_amdgcn_mfma_f32_16x16x32_bf16(ka1, qb[qf][1], S[qf][g], 0, 0, 0);
        }
      }

#pragma unroll
      for (int qf = 0; qf < 2; qf++)
#pragma unroll
        for (int g = 0; g < 4; g++) {
          bf16 pb4[4];
#pragma unroll
          for (int r = 0; r < 4; r++)
            pb4[r] = __float2bfloat16(__builtin_amdgcn_exp2f(S[qf][g][r]));
          const int chunk = 2 * g + (quad >> 1);
          *(short4v*)&Ps[wave][(qf * 16 + l16) * 64 + (chunk ^ sw8) * 8 + (quad & 1) * 4] =
              *(const short4v*)pb4;
        }

      short8 pb[2][2];
#pragma unroll
      for (int qf = 0; qf < 2; qf++) {
        pb[qf][0] = *(const short8*)&Ps[wave][(qf * 16 + l16) * 64 + ((quad    ) ^ sw8) * 8];
        pb[qf][1] = *(const short8*)&Ps[wave][(qf * 16 + l16) * 64 + ((quad + 4) ^ sw8) * 8];
        L[qf] = __builtin_amdgcn_mfma_f32_16x16x32_bf16(onesv, pb[qf][0], L[qf], 0, 0, 0);
        L[qf] = __builtin_amdgcn_mfma_f32_16x16x32_bf16(onesv, pb[qf][1], L[qf], 0, 0, 0);
      }

#pragma unroll
      for (int c = 0; c < 4; c++) {
        const short8 va0 = *(const short8*)&Vc[(c * 16 + l16) * 64 + ((quad    ) ^ sw8) * 8];
        const short8 va1 = *(const short8*)&Vc[(c * 16 + l16) * 64 + ((quad + 4) ^ sw8) * 8];
#pragma unroll
        for (int qf = 0; qf < 2; qf++) {
          O[qf][c] = __builtin_amdgcn_mfma_f32_16x16x32_bf16(va0, pb[qf][0], O[qf][c], 0, 0, 0);
          O[qf][c] = __builtin_amdgcn_mfma_f32_16x16x32_bf16(va1, pb[qf][1], O[qf][c], 0, 0, 0);
        }
      }
    }

    asm volatile("s_waitcnt vmcnt(0)" ::: "memory");
    __builtin_amdgcn_s_barrier();
    cur ^= 1;
  }

#pragma unroll
  for (int qf = 0; qf < 2; qf++) {
    const float inv = __builtin_amdgcn_rcpf(L[qf][0]);
    bf16* yrow = y + (size_t)(b * SEQ + q0 + qf * 16 + l16) * D_MODEL + h * HDIM + quad * 4;
#pragma unroll
    for (int c = 0; c < 4; c++) {
      bf16 ov[4];
#pragma unroll
      for (int r = 0; r < 4; r++) ov[r] = __float2bfloat16(O[qf][c][r] * inv);
      *(short4v*)(yrow + c * 16) = *(const short4v*)ov;
    }
  }
}

extern "C" void kernel_launch(void* const* d_in, const int* in_sizes, int n_in,
                              void* d_out, int out_size, void* d_ws, size_t ws_size,
                              hipStream_t stream) {
  const float* x      = (const float*)d_in[0];
  const float* ln1_g  = (const float*)d_in[1];
  const float* ln1_b  = (const float*)d_in[2];
  const float* ln2_g  = (const float*)d_in[3];
  const float* ln2_b  = (const float*)d_in[4];
  const float* w_qkv  = (const float*)d_in[5];
  const float* b_qkv  = (const float*)d_in[6];
  const float* w_proj = (const float*)d_in[7];
  const float* b_proj = (const float*)d_in[8];
  const float* w_fc1  = (const float*)d_in[9];
  const float* b_fc1  = (const float*)d_in[10];
  const float* w_fc2  = (const float*)d_in[11];
  const float* b_fc2  = (const float*)d_in[12];
  float* out = (float*)d_out;

  char* ws = (char*)d_ws;
  bf16*  h       = (bf16*)(ws);
  bf16*  qkv     = (bf16*)(ws + (8u  << 20));
  bf16*  wt_fc1  = (bf16*)(ws + (8u  << 20));
  bf16*  wt_fc2  = (bf16*)(ws + (16u << 20));
  bf16*  y       = (bf16*)(ws + (32u << 20));
  float* x1      = (float*)(ws + (40u << 20));
  bf16*  ffh     = (bf16*)(ws + (56u << 20));
  bf16*  wt_qkv  = (bf16*)(ws + (56u << 20));
  bf16*  wt_proj = (bf16*)(ws + (62u << 20));
  bf16*  vT      = (bf16*)(ws + (64u << 20));

  // qkv + proj weight converts (one dispatch)
  convert_w2<<<768 + 256, 256, 0, stream>>>(w_qkv, wt_qkv, 1024, 3072, 768,
                                            w_proj, wt_proj, 1024, 1024);
  // 1. h = LN1(x)
  ln_kernel<<<ROWS, 256, 0, stream>>>(x, ln1_g, ln1_b, h);
  // 2. qkv = h @ w_qkv + b_qkv   (256x256 phase-split, 16x12=192 blocks)
  gemm_256<0, bf16><<<192, 512, 0, stream>>>(
      h, wt_qkv, b_qkv, qkv, ROWS, 3072, D_MODEL, 12);
  // 2b. vT = V^T
  v_transpose<<<dim3(ROWS / 64, 1024 / 64), 256, 0, stream>>>(qkv, vT);
  // 3. y = softmax(q k^T / 8) v   (512 blocks, XCD co-located per (b,h))
  attn_mfma<<<512, 256, 0, stream>>>(qkv, vT, y);
  // fc1 + fc2 weight converts (one dispatch; must follow attn: overlays qkv)
  convert_w2<<<1024 + 1024, 256, 0, stream>>>(w_fc1, wt_fc1, 1024, 4096, 1024,
                                              w_fc2, wt_fc2, 4096, 1024);
  // 4. x1 = x + y @ w_proj + b_proj   (64x64 dbuf 2x2 waves, 64x16=1024 blocks)
  gemm64<true, float><<<1024, 256, 0, stream>>>(
      y, wt_proj, b_proj, x, x1, ROWS, D_MODEL, D_MODEL, 16);
  // 5. h = LN2(x1)
  ln_kernel<<<ROWS, 256, 0, stream>>>(x1, ln2_g, ln2_b, h);
  // 6. ffh = gelu(h @ w_fc1 + b_fc1)   (256x256 phase-split, 16x16=256 blocks)
  gemm_256<1, bf16><<<256, 512, 0, stream>>>(
      h, wt_fc1, b_fc1, ffh, ROWS, FFDIM, D_MODEL, 16);
  // 7. out = x1 + ffh @ w_fc2 + b_fc2   (64x64 dbuf 2x2 waves, 64x16=1024 blocks)
  gemm64<true, float><<<1024, 256, 0, stream>>>(
      ffh, wt_fc2, b_fc2, x1, out, ROWS, D_MODEL, FFDIM, 16);
}